// Round 7
// baseline (251.804 us; speedup 1.0000x reference)
//
#include <hip/hip_runtime.h>
#include <stdint.h>

#define L_DIM 1024
#define N_DIM 32
#define C_DIM 512
#define M_DIM (L_DIM * N_DIM)   // 32768 rows for the GEMMs
#define EPS_BN 1e-5f

typedef __attribute__((ext_vector_type(8))) short bf16x8;
typedef __attribute__((ext_vector_type(4))) float f32x4;

__device__ __forceinline__ unsigned short f2bf(float f) {
  union { float f; unsigned int u; } a; a.f = f;
  unsigned int u = a.u;
  return (unsigned short)((u + 0x7FFFu + ((u >> 16) & 1u)) >> 16); // RNE
}
__device__ __forceinline__ float bf2f(unsigned short h) {
  union { float f; unsigned int u; } a; a.u = ((unsigned int)h) << 16;
  return a.f;
}

// RNE-split two floats -> packed bf16 hi-pair, lo-pair (same math as old k_split)
__device__ __forceinline__ void split2rne(float f0, float f1, unsigned int& hi, unsigned int& lo) {
  unsigned short h0 = f2bf(f0), h1 = f2bf(f1);
  hi = (unsigned int)h0 | ((unsigned int)h1 << 16);
  unsigned short l0 = f2bf(f0 - bf2f(h0)), l1 = f2bf(f1 - bf2f(h1));
  lo = (unsigned int)l0 | ((unsigned int)l1 << 16);
}

__device__ __forceinline__ void gl16(const void* g, void* l) {
  __builtin_amdgcn_global_load_lds(
      (const __attribute__((address_space(1))) unsigned int*)g,
      (__attribute__((address_space(3))) unsigned int*)l, 16, 0, 0);
}

// ---------------- split fp32 -> bf16 hi/lo (weights only, W1+W2) ----------------
__global__ void k_split_w(const float* __restrict__ W1, const float* __restrict__ W2,
                          unsigned short* __restrict__ W1hi, unsigned short* __restrict__ W1lo,
                          unsigned short* __restrict__ W2hi, unsigned short* __restrict__ W2lo) {
  const int NW = C_DIM * C_DIM / 4;      // 65,536 float4 each
  int i = blockIdx.x * 256 + threadIdx.x;
  int stride = gridDim.x * 256;
  for (; i < 2 * NW; i += stride) {
    const float4* src; unsigned short* dh; unsigned short* dl; int j;
    if (i < NW) { src = (const float4*)W1; dh = W1hi; dl = W1lo; j = i; }
    else        { src = (const float4*)W2; dh = W2hi; dl = W2lo; j = i - NW; }
    float4 v = src[j];
    ushort4 h, l;
    h.x = f2bf(v.x); l.x = f2bf(v.x - bf2f(h.x));
    h.y = f2bf(v.y); l.y = f2bf(v.y - bf2f(h.y));
    h.z = f2bf(v.z); l.z = f2bf(v.z - bf2f(h.z));
    h.w = f2bf(v.w); l.w = f2bf(v.w - bf2f(h.w));
    ((ushort4*)dh)[j] = h;
    ((ushort4*)dl)[j] = l;
  }
}

// ---------------- bf16x3 MFMA GEMM: C = A(fp32) * B^T + bias, fused BN stats ----------------
// A: (M x K) fp32 row-major, reg-staged + RNE-split once per element -> LDS hi/lo.
// B: (N x K) bf16 hi/lo pre-split, gl16-staged. C: (M x N) fp32.
// 256x256 tile, BK=32, 512 threads = 8 waves (2M x 4N), wave-tile 128x64, monolithic
// KSTEP (R5 structure: 2 barriers + counted vmcnt(8), dbuf 128KB LDS, 1 block/CU).
__global__ __launch_bounds__(512, 2)
void k_gemm(const float* __restrict__ A,
            const unsigned short* __restrict__ Bhi, const unsigned short* __restrict__ Blo,
            const float* __restrict__ bias, float* __restrict__ C,
            float* __restrict__ gsum, float* __restrict__ gsq) {
  const int K = C_DIM;
  int d = blockIdx.x;
  int xcd = d & 7;
  int q = d >> 3;                  // 0..31
  int bm = xcd * 16 + (q >> 1);    // 0..127
  int bn = q & 1;                  // 0..1

  // per buffer (32768 ushort = 64KB): Ahi slots [0,1024), Alo [1024,2048),
  // Bhi [2048,3072), Blo [3072,4096); slot m = kc*256 + row, 16B each.
  __shared__ unsigned short lds[2][32768];   // 128 KB total

  int tid  = threadIdx.x;
  int lane = tid & 63;
  int wave = tid >> 6;
  int wm = wave >> 2;              // 0..1
  int wn = wave & 3;               // 0..3
  int lr = lane & 15;
  int lk = lane >> 4;

  f32x4 acc[8][4];
#pragma unroll
  for (int i = 0; i < 8; ++i)
#pragma unroll
    for (int j = 0; j < 4; ++j) acc[i][j] = (f32x4){0.f, 0.f, 0.f, 0.f};

  const int ra0 = tid & 255, ka0 = (tid >> 8) & 3;              // slot s0 = tid
  const int ra1 = (tid + 512) & 255, ka1 = ((tid + 512) >> 8) & 3;  // slot s1 = tid+512
  // A fp32: float4 indices (2 per slot)
  const float4* A4 = (const float4*)A;
  const int qa0 = ((bm * 256 + ra0) * K + ka0 * 8) >> 2;
  const int qa1 = ((bm * 256 + ra1) * K + ka1 * 8) >> 2;
  // B bf16: elem offsets
  const int ob0 = (bn * 256 + ra0) * K + ka0 * 8;
  const int ob1 = (bn * 256 + ra1) * K + ka1 * 8;

  // issue A fp32 loads for tile t into named float4 regs (8 float4 = 2 slots x 2)
#define AISSUE(R0, R1, R2, R3, t)            \
  do {                                       \
    R0 = A4[qa0 + (t) * 8];                  \
    R1 = A4[qa0 + 1 + (t) * 8];              \
    R2 = A4[qa1 + (t) * 8];                  \
    R3 = A4[qa1 + 1 + (t) * 8];              \
  } while (0)

  // split regs and write hi/lo into lds[buf] A-region (compiler inserts vmcnt)
#define AWRITE(buf, R0, R1, R2, R3)                               \
  do {                                                            \
    unsigned short* Lb = lds[buf];                                \
    union { unsigned int u[4]; bf16x8 v; } H0, L0, H1, L1;        \
    split2rne(R0.x, R0.y, H0.u[0], L0.u[0]);                      \
    split2rne(R0.z, R0.w, H0.u[1], L0.u[1]);                      \
    split2rne(R1.x, R1.y, H0.u[2], L0.u[2]);                      \
    split2rne(R1.z, R1.w, H0.u[3], L0.u[3]);                      \
    split2rne(R2.x, R2.y, H1.u[0], L1.u[0]);                      \
    split2rne(R2.z, R2.w, H1.u[1], L1.u[1]);                      \
    split2rne(R3.x, R3.y, H1.u[2], L1.u[2]);                      \
    split2rne(R3.z, R3.w, H1.u[3], L1.u[3]);                      \
    *(bf16x8*)(Lb + tid * 8) = H0.v;                              \
    *(bf16x8*)(Lb + 8192 + tid * 8) = L0.v;                       \
    *(bf16x8*)(Lb + (tid + 512) * 8) = H1.v;                      \
    *(bf16x8*)(Lb + 8192 + (tid + 512) * 8) = L1.v;               \
  } while (0)

#define BISSUE(buf, kk)                                         \
  do {                                                          \
    unsigned short* Lb = lds[buf];                              \
    gl16(Bhi + ob0 + (kk), Lb + (tid + 2048) * 8);              \
    gl16(Bhi + ob1 + (kk), Lb + (tid + 2560) * 8);              \
    gl16(Blo + ob0 + (kk), Lb + (tid + 3072) * 8);              \
    gl16(Blo + ob1 + (kk), Lb + (tid + 3584) * 8);              \
  } while (0)

#define HEAD(vm)                                                \
    asm volatile("s_waitcnt vmcnt(" #vm ")" ::: "memory");      \
    asm volatile("s_waitcnt lgkmcnt(0)" ::: "memory");          \
    __builtin_amdgcn_sched_barrier(0);                          \
    __builtin_amdgcn_s_barrier()

#define COMPUTE(buf)                                                          \
  do {                                                                        \
    const unsigned short* Lb = lds[buf];                                      \
    bf16x8 bh[4], bl[4], af[8];                                               \
    _Pragma("unroll")                                                         \
    for (int nj = 0; nj < 4; ++nj) {                                          \
      int slot = lk * 256 + wn * 64 + nj * 16 + lr;                           \
      bh[nj] = *(const bf16x8*)(Lb + 16384 + slot * 8);                       \
      bl[nj] = *(const bf16x8*)(Lb + 24576 + slot * 8);                       \
    }                                                                         \
    _Pragma("unroll")                                                         \
    for (int mi = 0; mi < 8; ++mi) {                                          \
      int slot = lk * 256 + wm * 128 + mi * 16 + lr;                          \
      af[mi] = *(const bf16x8*)(Lb + slot * 8);                               \
    }                                                                         \
    _Pragma("unroll")                                                         \
    for (int mi = 0; mi < 8; ++mi)                                            \
      _Pragma("unroll")                                                       \
      for (int nj = 0; nj < 4; ++nj)                                          \
        acc[mi][nj] = __builtin_amdgcn_mfma_f32_16x16x32_bf16(af[mi], bh[nj], acc[mi][nj], 0, 0, 0); \
    _Pragma("unroll")                                                         \
    for (int mi = 0; mi < 8; ++mi)                                            \
      _Pragma("unroll")                                                       \
      for (int nj = 0; nj < 4; ++nj)                                          \
        acc[mi][nj] = __builtin_amdgcn_mfma_f32_16x16x32_bf16(af[mi], bl[nj], acc[mi][nj], 0, 0, 0); \
    _Pragma("unroll")                                                         \
    for (int mi = 0; mi < 8; ++mi) {                                          \
      int slot = lk * 256 + wm * 128 + mi * 16 + lr;                          \
      af[mi] = *(const bf16x8*)(Lb + 8192 + slot * 8);                        \
    }                                                                         \
    _Pragma("unroll")                                                         \
    for (int mi = 0; mi < 8; ++mi)                                            \
      _Pragma("unroll")                                                       \
      for (int nj = 0; nj < 4; ++nj)                                          \
        acc[mi][nj] = __builtin_amdgcn_mfma_f32_16x16x32_bf16(af[mi], bh[nj], acc[mi][nj], 0, 0, 0); \
  } while (0)

  const int nt = C_DIM >> 5;                 // 16 K-steps (even)
  float4 aE0, aE1, aE2, aE3;                 // even-parity tile A regs
  float4 aO0, aO1, aO2, aO3;                 // odd-parity tile A regs

  // prologue: tiles 0,1 in flight; A(0) written to LDS
  AISSUE(aE0, aE1, aE2, aE3, 0);
  BISSUE(0, 0);
  AISSUE(aO0, aO1, aO2, aO3, 1);
  BISSUE(1, 32);
  AWRITE(0, aE0, aE1, aE2, aE3);             // compiler waits A(0) (vmcnt(12))

  // two K-steps per loop iteration -> static reg-set parity
  for (int tt = 0; tt < (nt >> 1) - 1; ++tt) {
    int t0 = tt * 2;                         // even tile, buffer 0
    // iter t0: compute buf0
    HEAD(8);                                 // drains B(t0)
    COMPUTE(0);
    __builtin_amdgcn_s_barrier();            // buf0 free
    if (t0 + 2 < nt) {
      AISSUE(aE0, aE1, aE2, aE3, t0 + 2);
      BISSUE(0, (t0 + 2) << 5);
    }
    AWRITE(1, aO0, aO1, aO2, aO3);           // write A(t0+1) into buf1 (waits its regs)
    // iter t0+1: compute buf1
    HEAD(8);                                 // drains B(t0+1)
    COMPUTE(1);
    __builtin_amdgcn_s_barrier();            // buf1 free
    if (t0 + 3 < nt) {
      AISSUE(aO0, aO1, aO2, aO3, t0 + 3);
      BISSUE(1, (t0 + 3) << 5);
    }
    AWRITE(0, aE0, aE1, aE2, aE3);           // write A(t0+2) into buf0
  }
  // tail: tiles nt-2 (buf0), nt-1 (buf1); A(nt-1) already written, B(nt-1) in flight
  HEAD(4);                                   // drains B(nt-2); B(nt-1) still out
  COMPUTE(0);
  __builtin_amdgcn_s_barrier();
  AWRITE(1, aO0, aO1, aO2, aO3);             // write A(nt-1) into buf1
  HEAD(0);                                   // drains B(nt-1)
  COMPUTE(1);

  // epilogue: C/D layout col = lane&15, row = (lane>>4)*4 + r; fused bias + BN partial stats
#pragma unroll
  for (int nj = 0; nj < 4; ++nj) {
    int gn = bn * 256 + wn * 64 + nj * 16 + lr;
    float bv = bias[gn];
    float s = 0.f, qq = 0.f;
#pragma unroll
    for (int mi = 0; mi < 8; ++mi) {
      int gm = bm * 256 + wm * 128 + mi * 16 + (lk << 2);
#pragma unroll
      for (int r = 0; r < 4; ++r) {
        float v = acc[mi][nj][r] + bv;
        C[(gm + r) * C_DIM + gn] = v;
        s += v; qq += v * v;
      }
    }
    s  += __shfl_xor(s, 16);  qq += __shfl_xor(qq, 16);
    s  += __shfl_xor(s, 32);  qq += __shfl_xor(qq, 32);
    if (lk == 0) {
      atomicAdd(&gsum[gn], s);
      atomicAdd(&gsq[gn], qq);
    }
  }
#undef AISSUE
#undef AWRITE
#undef BISSUE
#undef HEAD
#undef COMPUTE
}

// ---------------- parallel-scan IndRNN ----------------
// h_t = max(x_t + u h_{t-1}, 0). Maps h -> max(A + B h, M) form a monoid (B >= 0):
//   (A2,B2,M2) o (A1,B1,M1) = (A2 + B2*A1, B2*B1, max(A2 + B2*M1, M2))
// Block = 1024 threads = 16 waves; wave w owns L-rows [64w,64w+64) of 64 chains (lanes).
// Phase1: segment triple. Phase2: LDS prefix compose. Phase3: exact replay.

// BN(finalize inline) + IndRNN, emit h as fp32 for next GEMM's reg-staged A
__global__ __launch_bounds__(1024, 4)
void k_indrnn1(const float* __restrict__ y,
               const float* __restrict__ gsum, const float* __restrict__ gsq,
               const float* __restrict__ g, const float* __restrict__ be,
               const float* __restrict__ u, float* __restrict__ hout) {
  __shared__ float tA[1024], tB[1024], tM[1024];
  int lane = threadIdx.x & 63;
  int w = threadIdx.x >> 6;                 // segment 0..15
  int chain = blockIdx.x * 64 + lane;       // (n,c) flat index
  int c = chain & 511;
  float m  = gsum[c] * (1.0f / (float)M_DIM);
  float vv = gsq[c]  * (1.0f / (float)M_DIM) - m * m;
  float sc = g[c] * rsqrtf(vv + EPS_BN);
  float sh = be[c] - m * sc;
  float uu = u[c];
  const float* py = y + chain;
  const int base = w * 64;

  float A = 0.f, Bc = 1.f, Mx = 0.f;
  for (int c0 = 0; c0 < 64; c0 += 16) {
    float vb[16];
#pragma unroll
    for (int i = 0; i < 16; ++i) vb[i] = py[(base + c0 + i) * 16384];
#pragma unroll
    for (int i = 0; i < 16; ++i) {
      float xt = fmaf(vb[i], sc, sh);
      A  = fmaf(uu, A, xt);
      Mx = fmaxf(fmaf(uu, Mx, xt), 0.f);
      Bc *= uu;
    }
  }
  tA[w * 64 + lane] = A; tB[w * 64 + lane] = Bc; tM[w * 64 + lane] = Mx;
  __syncthreads();

  float pA = 0.f, pM = 0.f;
  for (int s = 0; s < w; ++s) {
    float a = tA[s * 64 + lane], b = tB[s * 64 + lane], mm = tM[s * 64 + lane];
    pA = fmaf(b, pA, a);
    pM = fmaxf(fmaf(b, pM, a), mm);
  }
  float h = fmaxf(pA, pM);        // h_start for this segment (h0 = 0)

  float* ph = hout + chain;
  for (int c0 = 0; c0 < 64; c0 += 16) {
    float vb[16];
#pragma unroll
    for (int i = 0; i < 16; ++i) vb[i] = py[(base + c0 + i) * 16384];
#pragma unroll
    for (int i = 0; i < 16; ++i) {
      float xt = fmaf(vb[i], sc, sh);
      h = fmaxf(fmaf(uu, h, xt), 0.f);
      ph[(base + c0 + i) * 16384] = h;
    }
  }
}

// BN(finalize inline) + IndRNN + residual, in place on d_out
__global__ __launch_bounds__(1024, 4)
void k_indrnn_res(float* __restrict__ y, const float* __restrict__ x,
                  const float* __restrict__ gsum, const float* __restrict__ gsq,
                  const float* __restrict__ g, const float* __restrict__ be,
                  const float* __restrict__ u) {
  __shared__ float tA[1024], tB[1024], tM[1024];
  int lane = threadIdx.x & 63;
  int w = threadIdx.x >> 6;
  int chain = blockIdx.x * 64 + lane;
  int c = chain & 511;
  float m  = gsum[c] * (1.0f / (float)M_DIM);
  float vv = gsq[c]  * (1.0f / (float)M_DIM) - m * m;
  float sc = g[c] * rsqrtf(vv + EPS_BN);
  float sh = be[c] - m * sc;
  float uu = u[c];
  float* py = y + chain;
  const float* px = x + chain;
  const int base = w * 64;

  float A = 0.f, Bc = 1.f, Mx = 0.f;
  for (int c0 = 0; c0 < 64; c0 += 16) {
    float vb[16];
#pragma unroll
    for (int i = 0; i < 16; ++i) vb[i] = py[(base + c0 + i) * 16384];
#pragma unroll
    for (int i = 0; i < 16; ++i) {
      float xt = fmaf(vb[i], sc, sh);
      A  = fmaf(uu, A, xt);
      Mx = fmaxf(fmaf(uu, Mx, xt), 0.f);
      Bc *= uu;
    }
  }
  tA[w * 64 + lane] = A; tB[w * 64 + lane] = Bc; tM[w * 64 + lane] = Mx;
  __syncthreads();

  float pA = 0.f, pM = 0.f;
  for (int s = 0; s < w; ++s) {
    float a = tA[s * 64 + lane], b = tB[s * 64 + lane], mm = tM[s * 64 + lane];
    pA = fmaf(b, pA, a);
    pM = fmaxf(fmaf(b, pM, a), mm);
  }
  float h = fmaxf(pA, pM);

  for (int c0 = 0; c0 < 64; c0 += 16) {
    float vb[16], xb[16];
#pragma unroll
    for (int i = 0; i < 16; ++i) vb[i] = py[(base + c0 + i) * 16384];
#pragma unroll
    for (int i = 0; i < 16; ++i) xb[i] = px[(base + c0 + i) * 16384];
#pragma unroll
    for (int i = 0; i < 16; ++i) {
      float xt = fmaf(vb[i], sc, sh);
      h = fmaxf(fmaf(uu, h, xt), 0.f);
      py[(base + c0 + i) * 16384] = h + xb[i];
    }
  }
}

extern "C" void kernel_launch(void* const* d_in, const int* in_sizes, int n_in,
                              void* d_out, int out_size, void* d_ws, size_t ws_size,
                              hipStream_t stream) {
  if (n_in < 11) return;
  const float* x   = (const float*)d_in[0];
  const float* W1  = (const float*)d_in[1];
  const float* b1  = (const float*)d_in[2];
  const float* g1  = (const float*)d_in[3];
  const float* be1 = (const float*)d_in[4];
  const float* u1  = (const float*)d_in[5];
  const float* W2  = (const float*)d_in[6];
  const float* b2  = (const float*)d_in[7];
  const float* g2  = (const float*)d_in[8];
  const float* be2 = (const float*)d_in[9];
  const float* u2  = (const float*)d_in[10];
  float* out = (float*)d_out;

  char* ws = (char*)d_ws;
  const size_t SZ_H1 = (size_t)M_DIM * C_DIM * sizeof(float);           // 67,108,864 B
  const size_t SZ_W  = (size_t)C_DIM * C_DIM * sizeof(unsigned short);  //    524,288 B
  float* h1 = (float*)ws;
  unsigned short* W1hi = (unsigned short*)(ws + SZ_H1);
  unsigned short* W1lo = W1hi + C_DIM * C_DIM;
  unsigned short* W2hi = W1lo + C_DIM * C_DIM;
  unsigned short* W2lo = W2hi + C_DIM * C_DIM;
  float* stats = (float*)(ws + SZ_H1 + 4 * SZ_W);
  float* sum1 = stats,        *sq1 = stats + 512;
  float* sum2 = stats + 1024, *sq2 = stats + 1536;
  if (ws_size < SZ_H1 + 4 * SZ_W + 4 * 512 * sizeof(float)) return;

  hipMemsetAsync(stats, 0, 4 * 512 * sizeof(float), stream);  // sum1,sq1,sum2,sq2

  k_split_w<<<512, 256, 0, stream>>>(W1, W2, W1hi, W1lo, W2hi, W2lo);

  dim3 gemmGrid(256);   // 1 block/CU
  k_gemm<<<gemmGrid, 512, 0, stream>>>(x, W1hi, W1lo, b1, out, sum1, sq1);
  k_indrnn1<<<256, 1024, 0, stream>>>(out, sum1, sq1, g1, be1, u1, h1);

  k_gemm<<<gemmGrid, 512, 0, stream>>>(h1, W2hi, W2lo, b2, out, sum2, sq2);
  k_indrnn_res<<<256, 1024, 0, stream>>>(out, x, sum2, sq2, g2, be2, u2);
}